// Round 7
// baseline (7078.632 us; speedup 1.0000x reference)
//
#include <hip/hip_runtime.h>
#include <cstddef>

// Problem constants (fixed by the reference)
static const int WW = 8192;     // width (atoms)
static const int DD = 768;      // input dim
static const int BBATCH = 8192; // batch
static const int KSEL = 32;     // MP steps

// ---------------------------------------------------------------------------
// column norms of Ad [D, W] -> nrm[W] = max(||Ad[:,w]||, 1e-8), fp64 accumulate
// ---------------------------------------------------------------------------
__global__ __launch_bounds__(256) void colnorm_kernel(const float* __restrict__ Ad,
                                                      float* __restrict__ nrm) {
    int w = blockIdx.x * 256 + threadIdx.x;
    double s = 0.0;
    for (int d = 0; d < DD; ++d) {
        double v = (double)Ad[(size_t)d * WW + w];
        s += v * v;
    }
    nrm[w] = fmaxf((float)sqrt(s), 1e-8f);
}

// ---------------------------------------------------------------------------
// AdnT[w, d] = Ad[d, w] / nrm[w]   (LDS tiled transpose, 32x32)
// ---------------------------------------------------------------------------
__global__ __launch_bounds__(256) void transpose_scale_kernel(const float* __restrict__ Ad,
                                                              const float* __restrict__ nrm,
                                                              float* __restrict__ AdnT) {
    __shared__ float tile[32][33];
    int wb = blockIdx.x * 32;
    int db = blockIdx.y * 32;
    int tx = threadIdx.x;   // 0..31
    int ty = threadIdx.y;   // 0..7
    for (int i = ty; i < 32; i += 8)
        tile[i][tx] = Ad[(size_t)(db + i) * WW + (wb + tx)];
    __syncthreads();
    for (int i = ty; i < 32; i += 8)
        AdnT[(size_t)(wb + i) * DD + (db + tx)] = tile[tx][i] / nrm[wb + i];
}

// ---------------------------------------------------------------------------
// Gram (TN, fp64): G[i,j] = (sum_d Ad[d,i]*Ad[d,j]) / (nrm[i]*nrm[j])
// UPPER 128x128 tiles only (bx >= by); mirror_kernel fills the lower half.
// 128x128 tile, BK=16, 256 threads, 8x8 fp64 microtile (2x2 blocks of 4x4,
// cols/rows split {g*4, 64+g*4} like the validated R2 geometry).
// LDS staged as DOUBLE (cvt once at staging; inner loop is pure f64 FMA).
// Epilogue math identical to R5's: acc * (1/nrm_i) / nrm_j.
// ---------------------------------------------------------------------------
__global__ __launch_bounds__(256) void gram_tn_f64_kernel(const float* __restrict__ Ad,
                                                          const float* __restrict__ nrm,
                                                          float* __restrict__ G) {
    if (blockIdx.x < blockIdx.y) return;   // symmetric: compute upper tiles only
    __shared__ __align__(16) double As[16 * 132];
    __shared__ __align__(16) double Bs[16 * 132];
    const int tid = threadIdx.x;
    const int tx = tid & 15;         // 0..15 (col group)
    const int ty = tid >> 4;         // 0..15 (row group)
    const int i0 = blockIdx.y * 128;
    const int j0 = blockIdx.x * 128;
    const int kr = tid >> 4;         // 0..15 staging k-row
    const int cb = (tid & 15) * 8;   // 0..120 staging col offset

    double acc[8][8];
#pragma unroll
    for (int i = 0; i < 8; ++i)
#pragma unroll
        for (int j = 0; j < 8; ++j) acc[i][j] = 0.0;

    for (int k0 = 0; k0 < DD; k0 += 16) {
        const float* arow = Ad + (size_t)(k0 + kr) * WW;
        float4 ai0 = *(const float4*)&arow[i0 + cb];
        float4 ai1 = *(const float4*)&arow[i0 + cb + 4];
        float4 bj0 = *(const float4*)&arow[j0 + cb];
        float4 bj1 = *(const float4*)&arow[j0 + cb + 4];
        __syncthreads();   // previous iteration's LDS reads done
        double* ap = &As[kr * 132 + cb];
        ap[0] = (double)ai0.x; ap[1] = (double)ai0.y;
        ap[2] = (double)ai0.z; ap[3] = (double)ai0.w;
        ap[4] = (double)ai1.x; ap[5] = (double)ai1.y;
        ap[6] = (double)ai1.z; ap[7] = (double)ai1.w;
        double* bp = &Bs[kr * 132 + cb];
        bp[0] = (double)bj0.x; bp[1] = (double)bj0.y;
        bp[2] = (double)bj0.z; bp[3] = (double)bj0.w;
        bp[4] = (double)bj1.x; bp[5] = (double)bj1.y;
        bp[6] = (double)bj1.z; bp[7] = (double)bj1.w;
        __syncthreads();

#pragma unroll
        for (int kk = 0; kk < 16; ++kk) {
            const double* arw = &As[kk * 132];
            const double* brw = &Bs[kk * 132];
            double av[8], bv[8];
#pragma unroll
            for (int e = 0; e < 4; ++e) {
                av[e]     = arw[ty * 4 + e];
                av[e + 4] = arw[64 + ty * 4 + e];
                bv[e]     = brw[tx * 4 + e];
                bv[e + 4] = brw[64 + tx * 4 + e];
            }
#pragma unroll
            for (int i = 0; i < 8; ++i)
#pragma unroll
                for (int j = 0; j < 8; ++j) acc[i][j] += av[i] * bv[j];
        }
    }

#pragma unroll
    for (int ia = 0; ia < 2; ++ia) {
#pragma unroll
        for (int i = 0; i < 4; ++i) {
            int row = i0 + ia * 64 + ty * 4 + i;
            double inv_i = 1.0 / (double)nrm[row];
            int ar = ia * 4 + i;
#pragma unroll
            for (int jb = 0; jb < 2; ++jb) {
#pragma unroll
                for (int j = 0; j < 4; ++j) {
                    int col = j0 + jb * 64 + tx * 4 + j;
                    G[(size_t)row * WW + col] =
                        (float)(acc[ar][jb * 4 + j] * inv_i / (double)nrm[col]);
                }
            }
        }
    }
}

// ---------------------------------------------------------------------------
// mirror: G[j,i] = G[i,j] for strict-upper 64x64 tiles (bitwise-exact copy)
// ---------------------------------------------------------------------------
__global__ __launch_bounds__(256) void mirror_kernel(float* __restrict__ G) {
    const int ti = blockIdx.y;
    const int tj = blockIdx.x;
    if (tj <= ti) return;
    __shared__ float tile[64][65];
    const int t = threadIdx.x;
    const int c4 = (t & 15) * 4;   // 0..60
    const int r  = t >> 4;         // 0..15
#pragma unroll
    for (int rr = r; rr < 64; rr += 16) {
        float4 v = *(const float4*)&G[(size_t)(ti * 64 + rr) * WW + tj * 64 + c4];
        tile[rr][c4 + 0] = v.x;
        tile[rr][c4 + 1] = v.y;
        tile[rr][c4 + 2] = v.z;
        tile[rr][c4 + 3] = v.w;
    }
    __syncthreads();
#pragma unroll
    for (int rr = r; rr < 64; rr += 16) {
        float4 v = make_float4(tile[c4 + 0][rr], tile[c4 + 1][rr],
                               tile[c4 + 2][rr], tile[c4 + 3][rr]);
        *(float4*)&G[(size_t)(tj * 64 + rr) * WW + ti * 64 + c4] = v;
    }
}

// ---------------------------------------------------------------------------
// z (NN, fp64): Z[b,w] = (sum_d (X[b,d]-bd[d]) * Ad[d,w]) / nrm[w]
// 128x128 tile, BK=16, 256 threads, 8x8 fp64 microtile, double-staged LDS.
// A staged transposed As[k][b]; B direct Bs[k][w].
// ---------------------------------------------------------------------------
__global__ __launch_bounds__(256) void z_nn_f64_kernel(const float* __restrict__ X,
                                                       const float* __restrict__ Ad,
                                                       const float* __restrict__ bd,
                                                       const float* __restrict__ nrm,
                                                       float* __restrict__ Z) {
    __shared__ __align__(16) double As[16 * 132];   // As[k][b]
    __shared__ __align__(16) double Bs[16 * 132];   // Bs[k][w]
    const int tid = threadIdx.x;
    const int tx = tid & 15;
    const int ty = tid >> 4;
    const int b0 = blockIdx.y * 128;
    const int w0 = blockIdx.x * 128;
    const int r  = tid >> 1;        // 0..127 (A staging batch-row)
    const int k8 = (tid & 1) * 8;   // 0 or 8 (A staging k offset)
    const int kr = tid >> 4;        // 0..15 (B staging k-row)
    const int cb = (tid & 15) * 8;  // 0..120

    double acc[8][8];
#pragma unroll
    for (int i = 0; i < 8; ++i)
#pragma unroll
        for (int j = 0; j < 8; ++j) acc[i][j] = 0.0;

    for (int k0 = 0; k0 < DD; k0 += 16) {
        float4 bias0 = *(const float4*)&bd[k0 + k8];
        float4 bias1 = *(const float4*)&bd[k0 + k8 + 4];
        float4 a0 = *(const float4*)&X[(size_t)(b0 + r) * DD + k0 + k8];
        float4 a1 = *(const float4*)&X[(size_t)(b0 + r) * DD + k0 + k8 + 4];
        a0.x -= bias0.x; a0.y -= bias0.y; a0.z -= bias0.z; a0.w -= bias0.w;
        a1.x -= bias1.x; a1.y -= bias1.y; a1.z -= bias1.z; a1.w -= bias1.w;
        const float* arow = Ad + (size_t)(k0 + kr) * WW;
        float4 bv0 = *(const float4*)&arow[w0 + cb];
        float4 bv1 = *(const float4*)&arow[w0 + cb + 4];
        __syncthreads();
        As[(k8 + 0) * 132 + r] = (double)a0.x;
        As[(k8 + 1) * 132 + r] = (double)a0.y;
        As[(k8 + 2) * 132 + r] = (double)a0.z;
        As[(k8 + 3) * 132 + r] = (double)a0.w;
        As[(k8 + 4) * 132 + r] = (double)a1.x;
        As[(k8 + 5) * 132 + r] = (double)a1.y;
        As[(k8 + 6) * 132 + r] = (double)a1.z;
        As[(k8 + 7) * 132 + r] = (double)a1.w;
        double* bp = &Bs[kr * 132 + cb];
        bp[0] = (double)bv0.x; bp[1] = (double)bv0.y;
        bp[2] = (double)bv0.z; bp[3] = (double)bv0.w;
        bp[4] = (double)bv1.x; bp[5] = (double)bv1.y;
        bp[6] = (double)bv1.z; bp[7] = (double)bv1.w;
        __syncthreads();

#pragma unroll
        for (int kk = 0; kk < 16; ++kk) {
            const double* arw = &As[kk * 132];
            const double* brw = &Bs[kk * 132];
            double av[8], bv[8];
#pragma unroll
            for (int e = 0; e < 4; ++e) {
                av[e]     = arw[ty * 4 + e];
                av[e + 4] = arw[64 + ty * 4 + e];
                bv[e]     = brw[tx * 4 + e];
                bv[e + 4] = brw[64 + tx * 4 + e];
            }
#pragma unroll
            for (int i = 0; i < 8; ++i)
#pragma unroll
                for (int j = 0; j < 8; ++j) acc[i][j] += av[i] * bv[j];
        }
    }

#pragma unroll
    for (int ia = 0; ia < 2; ++ia) {
#pragma unroll
        for (int i = 0; i < 4; ++i) {
            int row = b0 + ia * 64 + ty * 4 + i;
            int ar = ia * 4 + i;
#pragma unroll
            for (int jb = 0; jb < 2; ++jb) {
#pragma unroll
                for (int j = 0; j < 4; ++j) {
                    int col = w0 + jb * 64 + tx * 4 + j;
                    Z[(size_t)row * WW + col] =
                        (float)(acc[ar][jb * 4 + j] / (double)nrm[col]);
                }
            }
        }
    }
}

// ---------------------------------------------------------------------------
// Fused MP loop. One block per batch row; z-row in LDS for all 32 steps.
// Argmax tracking fused into the rank-1 update pass; wave64 shfl butterfly
// reduce + 4-partial LDS resolve -> 2 barriers per step.
// ---------------------------------------------------------------------------
__global__ __launch_bounds__(256) void mp_loop_kernel(const float* __restrict__ z0,
                                                      const float* __restrict__ G,
                                                      int* __restrict__ idxL,
                                                      float* __restrict__ valL) {
    __shared__ __align__(16) float zrow[WW];   // 32 KB
    __shared__ float wv[4];
    __shared__ int   wi[4];
    const int b = blockIdx.x;
    const int t = threadIdx.x;
    float4* zs = (float4*)zrow;

    float best = -1.f;
    int bidx = 0;
    unsigned selmask = 0;   // bit j*4+e: slot (t+256*j) element e is selected

    {
        const float4* zp = (const float4*)(z0 + (size_t)b * WW);
#pragma unroll
        for (int j = 0; j < 8; ++j) {
            int slot = t + 256 * j;
            float4 v = zp[slot];
            zs[slot] = v;
            int w = slot * 4;
            float a0 = fabsf(v.x), a1 = fabsf(v.y), a2 = fabsf(v.z), a3 = fabsf(v.w);
            if (a0 > best) { best = a0; bidx = w; }
            if (a1 > best) { best = a1; bidx = w + 1; }
            if (a2 > best) { best = a2; bidx = w + 2; }
            if (a3 > best) { best = a3; bidx = w + 3; }
        }
    }

    for (int k = 0; k < KSEL; ++k) {
        float v = best;
        int i = bidx;
#pragma unroll
        for (int off = 32; off > 0; off >>= 1) {
            float ov = __shfl_xor(v, off, 64);
            int   oi = __shfl_xor(i, off, 64);
            if (ov > v || (ov == v && oi < i)) { v = ov; i = oi; }
        }
        if ((t & 63) == 0) { wv[t >> 6] = v; wi[t >> 6] = i; }
        __syncthreads();   // A: partials visible; prev phase's zrow writes visible
        float rv = wv[0];
        int   ri = wi[0];
#pragma unroll
        for (int q = 1; q < 4; ++q) {
            float qv = wv[q];
            int   qi = wi[q];
            if (qv > rv || (qv == rv && qi < ri)) { rv = qv; ri = qi; }
        }
        const int idx = ri;
        const float val = zrow[idx];   // pre-update value (LDS broadcast)
        if (t == 0) {
            idxL[(size_t)b * KSEL + k] = idx;
            valL[(size_t)b * KSEL + k] = val;
        }
        if (((idx >> 2) & 255) == t)
            selmask |= 1u << (((idx >> 10) << 2) | (idx & 3));
        if (k == KSEL - 1) break;      // final update is dead work
        __syncthreads();   // B: all threads have read val before zrow changes

        best = -1.f;
        bidx = 0;
        const float4* gr = (const float4*)(G + (size_t)idx * WW);
#pragma unroll
        for (int j = 0; j < 8; ++j) {
            int slot = t + 256 * j;
            float4 g = gr[slot];
            float4 z = zs[slot];
            unsigned m = (selmask >> (j * 4)) & 0xFu;
            float n0 = (m & 1u) ? 0.f : z.x - val * g.x;
            float n1 = (m & 2u) ? 0.f : z.y - val * g.y;
            float n2 = (m & 4u) ? 0.f : z.z - val * g.z;
            float n3 = (m & 8u) ? 0.f : z.w - val * g.w;
            zs[slot] = make_float4(n0, n1, n2, n3);
            int w = slot * 4;
            float a0 = fabsf(n0), a1 = fabsf(n1), a2 = fabsf(n2), a3 = fabsf(n3);
            if (a0 > best) { best = a0; bidx = w; }
            if (a1 > best) { best = a1; bidx = w + 1; }
            if (a2 > best) { best = a2; bidx = w + 2; }
            if (a3 > best) { best = a3; bidx = w + 3; }
        }
    }
}

// ---------------------------------------------------------------------------
// copy idx/val metadata (d_out staging -> ws), element-wise
// ---------------------------------------------------------------------------
__global__ __launch_bounds__(256) void copy_meta_kernel(const int* __restrict__ si,
                                                        const float* __restrict__ sv,
                                                        int* __restrict__ di,
                                                        float* __restrict__ dv,
                                                        int n) {
    int i = blockIdx.x * 256 + threadIdx.x;
    if (i < n) {
        di[i] = si[i];
        dv[i] = sv[i];
    }
}

// ---------------------------------------------------------------------------
// out[row, :] = bd + sum_k val[b,k] * AdnT[idx[b,k], :]
// ---------------------------------------------------------------------------
__global__ __launch_bounds__(256) void assemble_kernel(const float* __restrict__ AdnT,
                                                       const float* __restrict__ bd,
                                                       const int* __restrict__ idxL,
                                                       const float* __restrict__ valL,
                                                       float* __restrict__ out,
                                                       int rowStart) {
    __shared__ int sidx[KSEL];
    __shared__ float sval[KSEL];
    const int b = blockIdx.x;
    const int row = rowStart + b;
    const int t = threadIdx.x;
    if (t < KSEL) {
        sidx[t] = idxL[(size_t)b * KSEL + t];
        sval[t] = valL[(size_t)b * KSEL + t];
    }
    __syncthreads();
    float acc0 = bd[t];
    float acc1 = bd[t + 256];
    float acc2 = bd[t + 512];
#pragma unroll 4
    for (int k = 0; k < KSEL; ++k) {
        const float* col = AdnT + (size_t)sidx[k] * DD;
        float v = sval[k];
        acc0 += v * col[t];
        acc1 += v * col[t + 256];
        acc2 += v * col[t + 512];
    }
    out[(size_t)row * DD + t] = acc0;
    out[(size_t)row * DD + t + 256] = acc1;
    out[(size_t)row * DD + t + 512] = acc2;
}

// ---------------------------------------------------------------------------
extern "C" void kernel_launch(void* const* d_in, const int* in_sizes, int n_in,
                              void* d_out, int out_size, void* d_ws, size_t ws_size,
                              hipStream_t stream) {
    const float* x  = (const float*)d_in[0];   // [B, D]
    const float* Ad = (const float*)d_in[1];   // [D, W]
    const float* bd = (const float*)d_in[2];   // [1, D]
    float* out = (float*)d_out;                // [B, D]

    const size_t ADNT_B = (size_t)WW * DD * 4;        // 25,165,824
    const size_t NRM_B  = (size_t)WW * 4;             // 32,768
    const size_t IDX_B  = (size_t)BBATCH * KSEL * 4;  // 1,048,576
    const size_t VAL_B  = IDX_B;
    const size_t G_B    = (size_t)WW * WW * 4;        // 268,435,456 (= 256 MiB)
    const size_t ZROW_B = (size_t)WW * 4;             // 32,768
    const size_t A_MIN  = ADNT_B + NRM_B + IDX_B + VAL_B + G_B + 128 * ZROW_B;

    if (ws_size >= A_MIN) {
        // ---------------- Layout A: everything in ws ----------------
        char* p = (char*)d_ws;
        float* AdnT = (float*)p;  p += ADNT_B;
        float* nrm  = (float*)p;  p += NRM_B;
        int*   idxL = (int*)p;    p += IDX_B;
        float* valL = (float*)p;  p += VAL_B;
        float* G    = (float*)p;  p += G_B;
        float* z    = (float*)p;
        size_t z_avail = ws_size - (ADNT_B + NRM_B + IDX_B + VAL_B + G_B);
        int chunk = (int)((z_avail / ZROW_B) / 128) * 128;
        if (chunk > BBATCH) chunk = BBATCH;

        colnorm_kernel<<<WW / 256, 256, 0, stream>>>(Ad, nrm);
        gram_tn_f64_kernel<<<dim3(WW / 128, WW / 128), 256, 0, stream>>>(Ad, nrm, G);
        mirror_kernel<<<dim3(WW / 64, WW / 64), 256, 0, stream>>>(G);
        for (int r0 = 0; r0 < BBATCH; r0 += chunk) {
            int rows = (BBATCH - r0 < chunk) ? (BBATCH - r0) : chunk;
            z_nn_f64_kernel<<<dim3(WW / 128, rows / 128), 256, 0, stream>>>(
                x + (size_t)r0 * DD, Ad, bd, nrm, z);
            mp_loop_kernel<<<rows, 256, 0, stream>>>(
                z, G, idxL + (size_t)r0 * KSEL, valL + (size_t)r0 * KSEL);
        }
        transpose_scale_kernel<<<dim3(WW / 32, DD / 32), dim3(32, 8), 0, stream>>>(Ad, nrm, AdnT);
        assemble_kernel<<<BBATCH, 256, 0, stream>>>(AdnT, bd, idxL, valL, out, 0);
    } else if (ws_size >= G_B) {
        // ---------------- Layout B: ws = G only; scratch in d_out ----------------
        // d_out carve (25,165,824 B total):
        //   [0 .. 20,971,520)          z chunks (640 rows x 32 KB)
        //   [20,971,520 .. 21,004,288) nrm (32 KB)
        //   [23,068,672 .. 24,117,248) idxL [B,32]
        //   [24,117,248 .. 25,165,824) valL [B,32]
        float* G    = (float*)d_ws;
        char*  ob   = (char*)d_out;
        float* z    = (float*)ob;
        float* nrm  = (float*)(ob + 20971520);
        int*   idxL = (int*)(ob + 23068672);
        float* valL = (float*)(ob + 24117248);
        // after MP loops, G is dead -> reuse ws:
        float* AdnT = (float*)d_ws;
        int*   idx2 = (int*)((char*)d_ws + ADNT_B);
        float* val2 = (float*)((char*)d_ws + ADNT_B + IDX_B);
        const int chunk = 640;   // multiple of 128 per full chunk; last = 512

        colnorm_kernel<<<WW / 256, 256, 0, stream>>>(Ad, nrm);
        gram_tn_f64_kernel<<<dim3(WW / 128, WW / 128), 256, 0, stream>>>(Ad, nrm, G);
        mirror_kernel<<<dim3(WW / 64, WW / 64), 256, 0, stream>>>(G);
        for (int r0 = 0; r0 < BBATCH; r0 += chunk) {
            int rows = (BBATCH - r0 < chunk) ? (BBATCH - r0) : chunk;
            z_nn_f64_kernel<<<dim3(WW / 128, rows / 128), 256, 0, stream>>>(
                x + (size_t)r0 * DD, Ad, bd, nrm, z);
            mp_loop_kernel<<<rows, 256, 0, stream>>>(
                z, G, idxL + (size_t)r0 * KSEL, valL + (size_t)r0 * KSEL);
        }
        // relocate metadata into ws (G dead), build AdnT in ws, then one
        // hazard-free assemble overwrites d_out.
        {
            int n = BBATCH * KSEL;
            copy_meta_kernel<<<(n + 255) / 256, 256, 0, stream>>>(idxL, valL, idx2, val2, n);
        }
        transpose_scale_kernel<<<dim3(WW / 32, DD / 32), dim3(32, 8), 0, stream>>>(Ad, nrm, AdnT);
        assemble_kernel<<<BBATCH, 256, 0, stream>>>(AdnT, bd, idx2, val2, out, 0);
    }
    // else: ws too small for any fp32-G plan -> leave output zeroed (clean fail)
}

// Round 8
// 5792.960 us; speedup vs baseline: 1.2219x; 1.2219x over previous
//
#include <hip/hip_runtime.h>
#include <cstddef>

// Problem constants (fixed by the reference)
static const int WW = 8192;     // width (atoms)
static const int DD = 768;      // input dim
static const int BBATCH = 8192; // batch
static const int KSEL = 32;     // MP steps

// ---------------------------------------------------------------------------
// column norms of Ad [D, W] -> nrm[W] = max(||Ad[:,w]||, 1e-8), fp64 accumulate
// ---------------------------------------------------------------------------
__global__ __launch_bounds__(256) void colnorm_kernel(const float* __restrict__ Ad,
                                                      float* __restrict__ nrm) {
    int w = blockIdx.x * 256 + threadIdx.x;
    double s = 0.0;
    for (int d = 0; d < DD; ++d) {
        double v = (double)Ad[(size_t)d * WW + w];
        s += v * v;
    }
    nrm[w] = fmaxf((float)sqrt(s), 1e-8f);
}

// ---------------------------------------------------------------------------
// AdnT[w, d] = Ad[d, w] / nrm[w]   (LDS tiled transpose, 32x32)
// ---------------------------------------------------------------------------
__global__ __launch_bounds__(256) void transpose_scale_kernel(const float* __restrict__ Ad,
                                                              const float* __restrict__ nrm,
                                                              float* __restrict__ AdnT) {
    __shared__ float tile[32][33];
    int wb = blockIdx.x * 32;
    int db = blockIdx.y * 32;
    int tx = threadIdx.x;   // 0..31
    int ty = threadIdx.y;   // 0..7
    for (int i = ty; i < 32; i += 8)
        tile[i][tx] = Ad[(size_t)(db + i) * WW + (wb + tx)];
    __syncthreads();
    for (int i = ty; i < 32; i += 8)
        AdnT[(size_t)(wb + i) * DD + (db + tx)] = tile[tx][i] / nrm[wb + i];
}

// ---------------------------------------------------------------------------
// Gram (TN, fp64): G[i,j] = (sum_d Ad[d,i]*Ad[d,j]) / (nrm[i]*nrm[j])
// UPPER 64x64 tiles only (bx >= by); mirror_kernel fills the lower half.
// 64x64 tile, BK=16, 256 threads, 4x4 fp64 microtile.
// LDS staged as DOUBLE (cvt once per 16 k-steps; inner loop pure f64 FMA).
// Fragment mapping: rows = ty*4+i (ty-broadcast reads, conflict-free);
// cols = j*16+tx (consecutive-double b64 reads -> 32 banks, conflict-free).
// Accumulation order and epilogue math identical to R5 -> bitwise-same G.
// ---------------------------------------------------------------------------
__global__ __launch_bounds__(256) void gram_tn_f64_kernel(const float* __restrict__ Ad,
                                                          const float* __restrict__ nrm,
                                                          float* __restrict__ G) {
    if (blockIdx.x < blockIdx.y) return;   // symmetric: compute upper tiles only
    __shared__ __align__(16) double As[16 * 66];
    __shared__ __align__(16) double Bs[16 * 66];
    const int tid = threadIdx.x;
    const int tx = tid & 15;         // 0..15 (col group)
    const int ty = tid >> 4;         // 0..15 (row group)
    const int i0 = blockIdx.y * 64;
    const int j0 = blockIdx.x * 64;
    const int kr = tid >> 4;         // 0..15 staging k-row
    const int cb = (tid & 15) * 4;   // 0..60 staging col offset

    double acc[4][4];
#pragma unroll
    for (int i = 0; i < 4; ++i)
#pragma unroll
        for (int j = 0; j < 4; ++j) acc[i][j] = 0.0;

    for (int k0 = 0; k0 < DD; k0 += 16) {
        const float* arow = Ad + (size_t)(k0 + kr) * WW;
        float4 ai = *(const float4*)&arow[i0 + cb];
        float4 bj = *(const float4*)&arow[j0 + cb];
        __syncthreads();   // previous iteration's LDS reads done
        double* ap = &As[kr * 66 + cb];
        ap[0] = (double)ai.x; ap[1] = (double)ai.y;
        ap[2] = (double)ai.z; ap[3] = (double)ai.w;
        double* bp = &Bs[kr * 66 + cb];
        bp[0] = (double)bj.x; bp[1] = (double)bj.y;
        bp[2] = (double)bj.z; bp[3] = (double)bj.w;
        __syncthreads();

#pragma unroll
        for (int kk = 0; kk < 16; ++kk) {
            const double* arw = &As[kk * 66 + ty * 4];
            const double* brw = &Bs[kk * 66];
            double av[4] = {arw[0], arw[1], arw[2], arw[3]};
            double bv[4] = {brw[tx], brw[16 + tx], brw[32 + tx], brw[48 + tx]};
#pragma unroll
            for (int i = 0; i < 4; ++i)
#pragma unroll
                for (int j = 0; j < 4; ++j) acc[i][j] += av[i] * bv[j];
        }
    }

#pragma unroll
    for (int i = 0; i < 4; ++i) {
        int row = i0 + ty * 4 + i;
        double inv_i = 1.0 / (double)nrm[row];
#pragma unroll
        for (int j = 0; j < 4; ++j) {
            int col = j0 + j * 16 + tx;
            G[(size_t)row * WW + col] = (float)(acc[i][j] * inv_i / (double)nrm[col]);
        }
    }
}

// ---------------------------------------------------------------------------
// mirror: G[j,i] = G[i,j] for strict-upper 64x64 tiles (bitwise-exact copy)
// ---------------------------------------------------------------------------
__global__ __launch_bounds__(256) void mirror_kernel(float* __restrict__ G) {
    const int ti = blockIdx.y;
    const int tj = blockIdx.x;
    if (tj <= ti) return;
    __shared__ float tile[64][65];
    const int t = threadIdx.x;
    const int c4 = (t & 15) * 4;   // 0..60
    const int r  = t >> 4;         // 0..15
#pragma unroll
    for (int rr = r; rr < 64; rr += 16) {
        float4 v = *(const float4*)&G[(size_t)(ti * 64 + rr) * WW + tj * 64 + c4];
        tile[rr][c4 + 0] = v.x;
        tile[rr][c4 + 1] = v.y;
        tile[rr][c4 + 2] = v.z;
        tile[rr][c4 + 3] = v.w;
    }
    __syncthreads();
#pragma unroll
    for (int rr = r; rr < 64; rr += 16) {
        float4 v = make_float4(tile[c4 + 0][rr], tile[c4 + 1][rr],
                               tile[c4 + 2][rr], tile[c4 + 3][rr]);
        *(float4*)&G[(size_t)(tj * 64 + rr) * WW + ti * 64 + c4] = v;
    }
}

// ---------------------------------------------------------------------------
// z (NN, fp64): Z[b,w] = (sum_d (X[b,d]-bd[d]) * Ad[d,w]) / nrm[w]
// Same double-staged 64x64 geometry; A staged transposed As[k][b], B direct.
// ---------------------------------------------------------------------------
__global__ __launch_bounds__(256) void z_nn_f64_kernel(const float* __restrict__ X,
                                                       const float* __restrict__ Ad,
                                                       const float* __restrict__ bd,
                                                       const float* __restrict__ nrm,
                                                       float* __restrict__ Z) {
    __shared__ __align__(16) double As[16 * 66];   // As[k][b]
    __shared__ __align__(16) double Bs[16 * 66];   // Bs[k][w]
    const int tid = threadIdx.x;
    const int tx = tid & 15;
    const int ty = tid >> 4;
    const int b0 = blockIdx.y * 64;
    const int w0 = blockIdx.x * 64;
    const int r  = tid >> 2;        // 0..63 (A staging batch-row)
    const int k4 = (tid & 3) * 4;   // 0,4,8,12 (A staging k offset)
    const int kr = tid >> 4;        // 0..15 (B staging k-row)
    const int cb = (tid & 15) * 4;  // 0..60

    double acc[4][4];
#pragma unroll
    for (int i = 0; i < 4; ++i)
#pragma unroll
        for (int j = 0; j < 4; ++j) acc[i][j] = 0.0;

    for (int k0 = 0; k0 < DD; k0 += 16) {
        float4 bias = *(const float4*)&bd[k0 + k4];
        float4 a = *(const float4*)&X[(size_t)(b0 + r) * DD + k0 + k4];
        a.x -= bias.x; a.y -= bias.y; a.z -= bias.z; a.w -= bias.w;
        const float* arow = Ad + (size_t)(k0 + kr) * WW;
        float4 bv4 = *(const float4*)&arow[w0 + cb];
        __syncthreads();
        As[(k4 + 0) * 66 + r] = (double)a.x;
        As[(k4 + 1) * 66 + r] = (double)a.y;
        As[(k4 + 2) * 66 + r] = (double)a.z;
        As[(k4 + 3) * 66 + r] = (double)a.w;
        double* bp = &Bs[kr * 66 + cb];
        bp[0] = (double)bv4.x; bp[1] = (double)bv4.y;
        bp[2] = (double)bv4.z; bp[3] = (double)bv4.w;
        __syncthreads();

#pragma unroll
        for (int kk = 0; kk < 16; ++kk) {
            const double* arw = &As[kk * 66 + ty * 4];
            const double* brw = &Bs[kk * 66];
            double av[4] = {arw[0], arw[1], arw[2], arw[3]};
            double bv[4] = {brw[tx], brw[16 + tx], brw[32 + tx], brw[48 + tx]};
#pragma unroll
            for (int i = 0; i < 4; ++i)
#pragma unroll
                for (int j = 0; j < 4; ++j) acc[i][j] += av[i] * bv[j];
        }
    }

#pragma unroll
    for (int i = 0; i < 4; ++i) {
        int row = b0 + ty * 4 + i;
#pragma unroll
        for (int j = 0; j < 4; ++j) {
            int col = w0 + j * 16 + tx;
            Z[(size_t)row * WW + col] = (float)(acc[i][j] / (double)nrm[col]);
        }
    }
}

// ---------------------------------------------------------------------------
// Fused MP loop. One block per batch row; z-row in LDS for all 32 steps.
// Argmax tracking fused into the rank-1 update pass; wave64 shfl butterfly
// reduce + 4-partial LDS resolve -> 2 barriers per step.
// ---------------------------------------------------------------------------
__global__ __launch_bounds__(256) void mp_loop_kernel(const float* __restrict__ z0,
                                                      const float* __restrict__ G,
                                                      int* __restrict__ idxL,
                                                      float* __restrict__ valL) {
    __shared__ __align__(16) float zrow[WW];   // 32 KB
    __shared__ float wv[4];
    __shared__ int   wi[4];
    const int b = blockIdx.x;
    const int t = threadIdx.x;
    float4* zs = (float4*)zrow;

    float best = -1.f;
    int bidx = 0;
    unsigned selmask = 0;   // bit j*4+e: slot (t+256*j) element e is selected

    {
        const float4* zp = (const float4*)(z0 + (size_t)b * WW);
#pragma unroll
        for (int j = 0; j < 8; ++j) {
            int slot = t + 256 * j;
            float4 v = zp[slot];
            zs[slot] = v;
            int w = slot * 4;
            float a0 = fabsf(v.x), a1 = fabsf(v.y), a2 = fabsf(v.z), a3 = fabsf(v.w);
            if (a0 > best) { best = a0; bidx = w; }
            if (a1 > best) { best = a1; bidx = w + 1; }
            if (a2 > best) { best = a2; bidx = w + 2; }
            if (a3 > best) { best = a3; bidx = w + 3; }
        }
    }

    for (int k = 0; k < KSEL; ++k) {
        float v = best;
        int i = bidx;
#pragma unroll
        for (int off = 32; off > 0; off >>= 1) {
            float ov = __shfl_xor(v, off, 64);
            int   oi = __shfl_xor(i, off, 64);
            if (ov > v || (ov == v && oi < i)) { v = ov; i = oi; }
        }
        if ((t & 63) == 0) { wv[t >> 6] = v; wi[t >> 6] = i; }
        __syncthreads();   // A: partials visible; prev phase's zrow writes visible
        float rv = wv[0];
        int   ri = wi[0];
#pragma unroll
        for (int q = 1; q < 4; ++q) {
            float qv = wv[q];
            int   qi = wi[q];
            if (qv > rv || (qv == rv && qi < ri)) { rv = qv; ri = qi; }
        }
        const int idx = ri;
        const float val = zrow[idx];   // pre-update value (LDS broadcast)
        if (t == 0) {
            idxL[(size_t)b * KSEL + k] = idx;
            valL[(size_t)b * KSEL + k] = val;
        }
        if (((idx >> 2) & 255) == t)
            selmask |= 1u << (((idx >> 10) << 2) | (idx & 3));
        if (k == KSEL - 1) break;      // final update is dead work
        __syncthreads();   // B: all threads have read val before zrow changes

        best = -1.f;
        bidx = 0;
        const float4* gr = (const float4*)(G + (size_t)idx * WW);
#pragma unroll
        for (int j = 0; j < 8; ++j) {
            int slot = t + 256 * j;
            float4 g = gr[slot];
            float4 z = zs[slot];
            unsigned m = (selmask >> (j * 4)) & 0xFu;
            float n0 = (m & 1u) ? 0.f : z.x - val * g.x;
            float n1 = (m & 2u) ? 0.f : z.y - val * g.y;
            float n2 = (m & 4u) ? 0.f : z.z - val * g.z;
            float n3 = (m & 8u) ? 0.f : z.w - val * g.w;
            zs[slot] = make_float4(n0, n1, n2, n3);
            int w = slot * 4;
            float a0 = fabsf(n0), a1 = fabsf(n1), a2 = fabsf(n2), a3 = fabsf(n3);
            if (a0 > best) { best = a0; bidx = w; }
            if (a1 > best) { best = a1; bidx = w + 1; }
            if (a2 > best) { best = a2; bidx = w + 2; }
            if (a3 > best) { best = a3; bidx = w + 3; }
        }
    }
}

// ---------------------------------------------------------------------------
// copy idx/val metadata (d_out staging -> ws), element-wise
// ---------------------------------------------------------------------------
__global__ __launch_bounds__(256) void copy_meta_kernel(const int* __restrict__ si,
                                                        const float* __restrict__ sv,
                                                        int* __restrict__ di,
                                                        float* __restrict__ dv,
                                                        int n) {
    int i = blockIdx.x * 256 + threadIdx.x;
    if (i < n) {
        di[i] = si[i];
        dv[i] = sv[i];
    }
}

// ---------------------------------------------------------------------------
// out[row, :] = bd + sum_k val[b,k] * AdnT[idx[b,k], :]
// ---------------------------------------------------------------------------
__global__ __launch_bounds__(256) void assemble_kernel(const float* __restrict__ AdnT,
                                                       const float* __restrict__ bd,
                                                       const int* __restrict__ idxL,
                                                       const float* __restrict__ valL,
                                                       float* __restrict__ out,
                                                       int rowStart) {
    __shared__ int sidx[KSEL];
    __shared__ float sval[KSEL];
    const int b = blockIdx.x;
    const int row = rowStart + b;
    const int t = threadIdx.x;
    if (t < KSEL) {
        sidx[t] = idxL[(size_t)b * KSEL + t];
        sval[t] = valL[(size_t)b * KSEL + t];
    }
    __syncthreads();
    float acc0 = bd[t];
    float acc1 = bd[t + 256];
    float acc2 = bd[t + 512];
#pragma unroll 4
    for (int k = 0; k < KSEL; ++k) {
        const float* col = AdnT + (size_t)sidx[k] * DD;
        float v = sval[k];
        acc0 += v * col[t];
        acc1 += v * col[t + 256];
        acc2 += v * col[t + 512];
    }
    out[(size_t)row * DD + t] = acc0;
    out[(size_t)row * DD + t + 256] = acc1;
    out[(size_t)row * DD + t + 512] = acc2;
}

// ---------------------------------------------------------------------------
extern "C" void kernel_launch(void* const* d_in, const int* in_sizes, int n_in,
                              void* d_out, int out_size, void* d_ws, size_t ws_size,
                              hipStream_t stream) {
    const float* x  = (const float*)d_in[0];   // [B, D]
    const float* Ad = (const float*)d_in[1];   // [D, W]
    const float* bd = (const float*)d_in[2];   // [1, D]
    float* out = (float*)d_out;                // [B, D]

    const size_t ADNT_B = (size_t)WW * DD * 4;        // 25,165,824
    const size_t NRM_B  = (size_t)WW * 4;             // 32,768
    const size_t IDX_B  = (size_t)BBATCH * KSEL * 4;  // 1,048,576
    const size_t VAL_B  = IDX_B;
    const size_t G_B    = (size_t)WW * WW * 4;        // 268,435,456 (= 256 MiB)
    const size_t ZROW_B = (size_t)WW * 4;             // 32,768
    const size_t A_MIN  = ADNT_B + NRM_B + IDX_B + VAL_B + G_B + 128 * ZROW_B;

    if (ws_size >= A_MIN) {
        // ---------------- Layout A: everything in ws ----------------
        char* p = (char*)d_ws;
        float* AdnT = (float*)p;  p += ADNT_B;
        float* nrm  = (float*)p;  p += NRM_B;
        int*   idxL = (int*)p;    p += IDX_B;
        float* valL = (float*)p;  p += VAL_B;
        float* G    = (float*)p;  p += G_B;
        float* z    = (float*)p;
        size_t z_avail = ws_size - (ADNT_B + NRM_B + IDX_B + VAL_B + G_B);
        int chunk = (int)((z_avail / ZROW_B) / 128) * 128;
        if (chunk > BBATCH) chunk = BBATCH;

        colnorm_kernel<<<WW / 256, 256, 0, stream>>>(Ad, nrm);
        gram_tn_f64_kernel<<<dim3(WW / 64, WW / 64), 256, 0, stream>>>(Ad, nrm, G);
        mirror_kernel<<<dim3(WW / 64, WW / 64), 256, 0, stream>>>(G);
        for (int r0 = 0; r0 < BBATCH; r0 += chunk) {
            int rows = (BBATCH - r0 < chunk) ? (BBATCH - r0) : chunk;
            z_nn_f64_kernel<<<dim3(WW / 64, rows / 64), 256, 0, stream>>>(
                x + (size_t)r0 * DD, Ad, bd, nrm, z);
            mp_loop_kernel<<<rows, 256, 0, stream>>>(
                z, G, idxL + (size_t)r0 * KSEL, valL + (size_t)r0 * KSEL);
        }
        transpose_scale_kernel<<<dim3(WW / 32, DD / 32), dim3(32, 8), 0, stream>>>(Ad, nrm, AdnT);
        assemble_kernel<<<BBATCH, 256, 0, stream>>>(AdnT, bd, idxL, valL, out, 0);
    } else if (ws_size >= G_B) {
        // ---------------- Layout B: ws = G only; scratch in d_out ----------------
        // d_out carve (25,165,824 B total):
        //   [0 .. 20,971,520)          z chunks (640 rows x 32 KB)
        //   [20,971,520 .. 21,004,288) nrm (32 KB)
        //   [23,068,672 .. 24,117,248) idxL [B,32]
        //   [24,117,248 .. 25,165,824) valL [B,32]
        float* G    = (float*)d_ws;
        char*  ob   = (char*)d_out;
        float* z    = (float*)ob;
        float* nrm  = (float*)(ob + 20971520);
        int*   idxL = (int*)(ob + 23068672);
        float* valL = (float*)(ob + 24117248);
        // after MP loops, G is dead -> reuse ws:
        float* AdnT = (float*)d_ws;
        int*   idx2 = (int*)((char*)d_ws + ADNT_B);
        float* val2 = (float*)((char*)d_ws + ADNT_B + IDX_B);
        const int chunk = 640;   // multiple of 64; last chunk = 512

        colnorm_kernel<<<WW / 256, 256, 0, stream>>>(Ad, nrm);
        gram_tn_f64_kernel<<<dim3(WW / 64, WW / 64), 256, 0, stream>>>(Ad, nrm, G);
        mirror_kernel<<<dim3(WW / 64, WW / 64), 256, 0, stream>>>(G);
        for (int r0 = 0; r0 < BBATCH; r0 += chunk) {
            int rows = (BBATCH - r0 < chunk) ? (BBATCH - r0) : chunk;
            z_nn_f64_kernel<<<dim3(WW / 64, rows / 64), 256, 0, stream>>>(
                x + (size_t)r0 * DD, Ad, bd, nrm, z);
            mp_loop_kernel<<<rows, 256, 0, stream>>>(
                z, G, idxL + (size_t)r0 * KSEL, valL + (size_t)r0 * KSEL);
        }
        // relocate metadata into ws (G dead), build AdnT in ws, then one
        // hazard-free assemble overwrites d_out.
        {
            int n = BBATCH * KSEL;
            copy_meta_kernel<<<(n + 255) / 256, 256, 0, stream>>>(idxL, valL, idx2, val2, n);
        }
        transpose_scale_kernel<<<dim3(WW / 32, DD / 32), dim3(32, 8), 0, stream>>>(Ad, nrm, AdnT);
        assemble_kernel<<<BBATCH, 256, 0, stream>>>(AdnT, bd, idx2, val2, out, 0);
    }
    // else: ws too small for any fp32-G plan -> leave output zeroed (clean fail)
}

// Round 9
// 5623.369 us; speedup vs baseline: 1.2588x; 1.0302x over previous
//
#include <hip/hip_runtime.h>
#include <cstddef>

// Problem constants (fixed by the reference)
static const int WW = 8192;     // width (atoms)
static const int DD = 768;      // input dim
static const int BBATCH = 8192; // batch
static const int KSEL = 32;     // MP steps

// ---------------------------------------------------------------------------
// column norms of Ad [D, W] -> nrm[W] = max(||Ad[:,w]||, 1e-8), fp64 accumulate
// ---------------------------------------------------------------------------
__global__ __launch_bounds__(256) void colnorm_kernel(const float* __restrict__ Ad,
                                                      float* __restrict__ nrm) {
    int w = blockIdx.x * 256 + threadIdx.x;
    double s = 0.0;
    for (int d = 0; d < DD; ++d) {
        double v = (double)Ad[(size_t)d * WW + w];
        s += v * v;
    }
    nrm[w] = fmaxf((float)sqrt(s), 1e-8f);
}

// ---------------------------------------------------------------------------
// AdnT[w, d] = Ad[d, w] / nrm[w]   (LDS tiled transpose, 32x32)
// ---------------------------------------------------------------------------
__global__ __launch_bounds__(256) void transpose_scale_kernel(const float* __restrict__ Ad,
                                                              const float* __restrict__ nrm,
                                                              float* __restrict__ AdnT) {
    __shared__ float tile[32][33];
    int wb = blockIdx.x * 32;
    int db = blockIdx.y * 32;
    int tx = threadIdx.x;   // 0..31
    int ty = threadIdx.y;   // 0..7
    for (int i = ty; i < 32; i += 8)
        tile[i][tx] = Ad[(size_t)(db + i) * WW + (wb + tx)];
    __syncthreads();
    for (int i = ty; i < 32; i += 8)
        AdnT[(size_t)(wb + i) * DD + (db + tx)] = tile[tx][i] / nrm[wb + i];
}

// ---------------------------------------------------------------------------
// Gram (TN, fp64): G[i,j] = (sum_d Ad[d,i]*Ad[d,j]) / (nrm[i]*nrm[j])
// 128x64 tile, BK=16, 256 threads, 8x4 f64 microtile.
// A staged f32 (cvt in loop, 8 per 32 FMA); B staged f64 with lane-contiguous
// double2 writes (conflict-free) -> no B cvt in the inner loop.
// Upper-region blocks only (bx >= 2*by); mirror fills strict-lower tiles
// (straddling blocks' lower-tile elements are recomputed bitwise-identically).
// Per-element k-order identical to R5/R8 -> bitwise-same G.
// ---------------------------------------------------------------------------
__global__ __launch_bounds__(256) void gram_tn_f64_kernel(const float* __restrict__ Ad,
                                                          const float* __restrict__ nrm,
                                                          float* __restrict__ G) {
    const int bx = blockIdx.x, by = blockIdx.y;
    if (bx < 2 * by) return;   // block entirely strictly-lower -> skip
    __shared__ __align__(16) float  As[16 * 132];
    __shared__ __align__(16) double Bs[16 * 66];
    const int tid = threadIdx.x;
    const int tx = tid & 15;         // 0..15 (col group)
    const int ty = tid >> 4;         // 0..15 (row group)
    const int i0 = by * 128;
    const int j0 = bx * 64;
    const int kr = tid >> 4;         // A staging k-row 0..15
    const int cb = (tid & 15) * 4;   // A staging col offset
    const int brow = tid >> 5;       // B staging k-row 0..7 (+8 second)
    const int bpos = (tid & 31) * 2; // B staging col offset 0..62

    double acc[8][4];
#pragma unroll
    for (int i = 0; i < 8; ++i)
#pragma unroll
        for (int j = 0; j < 4; ++j) acc[i][j] = 0.0;

    for (int k0 = 0; k0 < DD; k0 += 16) {
        const float* arow = Ad + (size_t)(k0 + kr) * WW;
        float4 a0 = *(const float4*)&arow[i0 + cb];
        float4 a1 = *(const float4*)&arow[i0 + 64 + cb];
        float2 bl0 = *(const float2*)&Ad[(size_t)(k0 + brow) * WW + j0 + bpos];
        float2 bl1 = *(const float2*)&Ad[(size_t)(k0 + 8 + brow) * WW + j0 + bpos];
        __syncthreads();   // previous iteration's LDS reads done
        *(float4*)&As[kr * 132 + cb] = a0;
        *(float4*)&As[kr * 132 + 64 + cb] = a1;
        double2 d0; d0.x = (double)bl0.x; d0.y = (double)bl0.y;
        double2 d1; d1.x = (double)bl1.x; d1.y = (double)bl1.y;
        *(double2*)&Bs[brow * 66 + bpos] = d0;
        *(double2*)&Bs[(8 + brow) * 66 + bpos] = d1;
        __syncthreads();

#pragma unroll
        for (int kk = 0; kk < 16; ++kk) {
            float4 af0 = *(const float4*)&As[kk * 132 + ty * 4];
            float4 af1 = *(const float4*)&As[kk * 132 + 64 + ty * 4];
            const double* bb = &Bs[kk * 66];
            double av[8] = {(double)af0.x, (double)af0.y, (double)af0.z, (double)af0.w,
                            (double)af1.x, (double)af1.y, (double)af1.z, (double)af1.w};
            double bv[4] = {bb[tx], bb[16 + tx], bb[32 + tx], bb[48 + tx]};
#pragma unroll
            for (int i = 0; i < 8; ++i)
#pragma unroll
                for (int j = 0; j < 4; ++j) acc[i][j] += av[i] * bv[j];
        }
    }

#pragma unroll
    for (int band = 0; band < 2; ++band) {
#pragma unroll
        for (int i = 0; i < 4; ++i) {
            int row = i0 + band * 64 + ty * 4 + i;
            double inv_i = 1.0 / (double)nrm[row];
            int ar = band * 4 + i;
#pragma unroll
            for (int j = 0; j < 4; ++j) {
                int col = j0 + j * 16 + tx;
                G[(size_t)row * WW + col] = (float)(acc[ar][j] * inv_i / (double)nrm[col]);
            }
        }
    }
}

// ---------------------------------------------------------------------------
// mirror: G[j,i] = G[i,j] for strict-upper 64x64 tiles (bitwise-exact copy)
// ---------------------------------------------------------------------------
__global__ __launch_bounds__(256) void mirror_kernel(float* __restrict__ G) {
    const int ti = blockIdx.y;
    const int tj = blockIdx.x;
    if (tj <= ti) return;
    __shared__ float tile[64][65];
    const int t = threadIdx.x;
    const int c4 = (t & 15) * 4;   // 0..60
    const int r  = t >> 4;         // 0..15
#pragma unroll
    for (int rr = r; rr < 64; rr += 16) {
        float4 v = *(const float4*)&G[(size_t)(ti * 64 + rr) * WW + tj * 64 + c4];
        tile[rr][c4 + 0] = v.x;
        tile[rr][c4 + 1] = v.y;
        tile[rr][c4 + 2] = v.z;
        tile[rr][c4 + 3] = v.w;
    }
    __syncthreads();
#pragma unroll
    for (int rr = r; rr < 64; rr += 16) {
        float4 v = make_float4(tile[c4 + 0][rr], tile[c4 + 1][rr],
                               tile[c4 + 2][rr], tile[c4 + 3][rr]);
        *(float4*)&G[(size_t)(tj * 64 + rr) * WW + ti * 64 + c4] = v;
    }
}

// ---------------------------------------------------------------------------
// z (NN, fp64): Z[b,w] = (sum_d (X[b,d]-bd[d]) * Ad[d,w]) / nrm[w]
// Same 128x64 / 8x4 geometry; A (=X-bd) staged f32 transposed As[k][b],
// B staged f64 contiguous.
// ---------------------------------------------------------------------------
__global__ __launch_bounds__(256) void z_nn_f64_kernel(const float* __restrict__ X,
                                                       const float* __restrict__ Ad,
                                                       const float* __restrict__ bd,
                                                       const float* __restrict__ nrm,
                                                       float* __restrict__ Z) {
    __shared__ __align__(16) float  As[16 * 132];   // As[k][b]
    __shared__ __align__(16) double Bs[16 * 66];    // Bs[k][w]
    const int tid = threadIdx.x;
    const int tx = tid & 15;
    const int ty = tid >> 4;
    const int b0 = blockIdx.y * 128;
    const int w0 = blockIdx.x * 64;
    const int r  = tid >> 1;         // 0..127 (A staging batch-row)
    const int k8 = (tid & 1) * 8;    // 0 or 8 (A staging k offset)
    const int brow = tid >> 5;       // 0..7
    const int bpos = (tid & 31) * 2; // 0..62

    double acc[8][4];
#pragma unroll
    for (int i = 0; i < 8; ++i)
#pragma unroll
        for (int j = 0; j < 4; ++j) acc[i][j] = 0.0;

    for (int k0 = 0; k0 < DD; k0 += 16) {
        float4 bias0 = *(const float4*)&bd[k0 + k8];
        float4 bias1 = *(const float4*)&bd[k0 + k8 + 4];
        float4 a0 = *(const float4*)&X[(size_t)(b0 + r) * DD + k0 + k8];
        float4 a1 = *(const float4*)&X[(size_t)(b0 + r) * DD + k0 + k8 + 4];
        a0.x -= bias0.x; a0.y -= bias0.y; a0.z -= bias0.z; a0.w -= bias0.w;
        a1.x -= bias1.x; a1.y -= bias1.y; a1.z -= bias1.z; a1.w -= bias1.w;
        float2 bl0 = *(const float2*)&Ad[(size_t)(k0 + brow) * WW + w0 + bpos];
        float2 bl1 = *(const float2*)&Ad[(size_t)(k0 + 8 + brow) * WW + w0 + bpos];
        __syncthreads();
        As[(k8 + 0) * 132 + r] = a0.x;
        As[(k8 + 1) * 132 + r] = a0.y;
        As[(k8 + 2) * 132 + r] = a0.z;
        As[(k8 + 3) * 132 + r] = a0.w;
        As[(k8 + 4) * 132 + r] = a1.x;
        As[(k8 + 5) * 132 + r] = a1.y;
        As[(k8 + 6) * 132 + r] = a1.z;
        As[(k8 + 7) * 132 + r] = a1.w;
        double2 d0; d0.x = (double)bl0.x; d0.y = (double)bl0.y;
        double2 d1; d1.x = (double)bl1.x; d1.y = (double)bl1.y;
        *(double2*)&Bs[brow * 66 + bpos] = d0;
        *(double2*)&Bs[(8 + brow) * 66 + bpos] = d1;
        __syncthreads();

#pragma unroll
        for (int kk = 0; kk < 16; ++kk) {
            float4 af0 = *(const float4*)&As[kk * 132 + ty * 4];
            float4 af1 = *(const float4*)&As[kk * 132 + 64 + ty * 4];
            const double* bb = &Bs[kk * 66];
            double av[8] = {(double)af0.x, (double)af0.y, (double)af0.z, (double)af0.w,
                            (double)af1.x, (double)af1.y, (double)af1.z, (double)af1.w};
            double bv[4] = {bb[tx], bb[16 + tx], bb[32 + tx], bb[48 + tx]};
#pragma unroll
            for (int i = 0; i < 8; ++i)
#pragma unroll
                for (int j = 0; j < 4; ++j) acc[i][j] += av[i] * bv[j];
        }
    }

#pragma unroll
    for (int band = 0; band < 2; ++band) {
#pragma unroll
        for (int i = 0; i < 4; ++i) {
            int row = b0 + band * 64 + ty * 4 + i;
            int ar = band * 4 + i;
#pragma unroll
            for (int j = 0; j < 4; ++j) {
                int col = w0 + j * 16 + tx;
                Z[(size_t)row * WW + col] = (float)(acc[ar][j] / (double)nrm[col]);
            }
        }
    }
}

// ---------------------------------------------------------------------------
// Fused MP loop. One block per batch row; z-row in LDS for all 32 steps.
// Argmax tracking fused into the rank-1 update pass; wave64 shfl butterfly
// reduce + 4-partial LDS resolve -> 2 barriers per step.
// ---------------------------------------------------------------------------
__global__ __launch_bounds__(256) void mp_loop_kernel(const float* __restrict__ z0,
                                                      const float* __restrict__ G,
                                                      int* __restrict__ idxL,
                                                      float* __restrict__ valL) {
    __shared__ __align__(16) float zrow[WW];   // 32 KB
    __shared__ float wv[4];
    __shared__ int   wi[4];
    const int b = blockIdx.x;
    const int t = threadIdx.x;
    float4* zs = (float4*)zrow;

    float best = -1.f;
    int bidx = 0;
    unsigned selmask = 0;   // bit j*4+e: slot (t+256*j) element e is selected

    {
        const float4* zp = (const float4*)(z0 + (size_t)b * WW);
#pragma unroll
        for (int j = 0; j < 8; ++j) {
            int slot = t + 256 * j;
            float4 v = zp[slot];
            zs[slot] = v;
            int w = slot * 4;
            float a0 = fabsf(v.x), a1 = fabsf(v.y), a2 = fabsf(v.z), a3 = fabsf(v.w);
            if (a0 > best) { best = a0; bidx = w; }
            if (a1 > best) { best = a1; bidx = w + 1; }
            if (a2 > best) { best = a2; bidx = w + 2; }
            if (a3 > best) { best = a3; bidx = w + 3; }
        }
    }

    for (int k = 0; k < KSEL; ++k) {
        float v = best;
        int i = bidx;
#pragma unroll
        for (int off = 32; off > 0; off >>= 1) {
            float ov = __shfl_xor(v, off, 64);
            int   oi = __shfl_xor(i, off, 64);
            if (ov > v || (ov == v && oi < i)) { v = ov; i = oi; }
        }
        if ((t & 63) == 0) { wv[t >> 6] = v; wi[t >> 6] = i; }
        __syncthreads();   // A: partials visible; prev phase's zrow writes visible
        float rv = wv[0];
        int   ri = wi[0];
#pragma unroll
        for (int q = 1; q < 4; ++q) {
            float qv = wv[q];
            int   qi = wi[q];
            if (qv > rv || (qv == rv && qi < ri)) { rv = qv; ri = qi; }
        }
        const int idx = ri;
        const float val = zrow[idx];   // pre-update value (LDS broadcast)
        if (t == 0) {
            idxL[(size_t)b * KSEL + k] = idx;
            valL[(size_t)b * KSEL + k] = val;
        }
        if (((idx >> 2) & 255) == t)
            selmask |= 1u << (((idx >> 10) << 2) | (idx & 3));
        if (k == KSEL - 1) break;      // final update is dead work
        __syncthreads();   // B: all threads have read val before zrow changes

        best = -1.f;
        bidx = 0;
        const float4* gr = (const float4*)(G + (size_t)idx * WW);
#pragma unroll
        for (int j = 0; j < 8; ++j) {
            int slot = t + 256 * j;
            float4 g = gr[slot];
            float4 z = zs[slot];
            unsigned m = (selmask >> (j * 4)) & 0xFu;
            float n0 = (m & 1u) ? 0.f : z.x - val * g.x;
            float n1 = (m & 2u) ? 0.f : z.y - val * g.y;
            float n2 = (m & 4u) ? 0.f : z.z - val * g.z;
            float n3 = (m & 8u) ? 0.f : z.w - val * g.w;
            zs[slot] = make_float4(n0, n1, n2, n3);
            int w = slot * 4;
            float a0 = fabsf(n0), a1 = fabsf(n1), a2 = fabsf(n2), a3 = fabsf(n3);
            if (a0 > best) { best = a0; bidx = w; }
            if (a1 > best) { best = a1; bidx = w + 1; }
            if (a2 > best) { best = a2; bidx = w + 2; }
            if (a3 > best) { best = a3; bidx = w + 3; }
        }
    }
}

// ---------------------------------------------------------------------------
// copy idx/val metadata (d_out staging -> ws), element-wise
// ---------------------------------------------------------------------------
__global__ __launch_bounds__(256) void copy_meta_kernel(const int* __restrict__ si,
                                                        const float* __restrict__ sv,
                                                        int* __restrict__ di,
                                                        float* __restrict__ dv,
                                                        int n) {
    int i = blockIdx.x * 256 + threadIdx.x;
    if (i < n) {
        di[i] = si[i];
        dv[i] = sv[i];
    }
}

// ---------------------------------------------------------------------------
// out[row, :] = bd + sum_k val[b,k] * AdnT[idx[b,k], :]
// ---------------------------------------------------------------------------
__global__ __launch_bounds__(256) void assemble_kernel(const float* __restrict__ AdnT,
                                                       const float* __restrict__ bd,
                                                       const int* __restrict__ idxL,
                                                       const float* __restrict__ valL,
                                                       float* __restrict__ out,
                                                       int rowStart) {
    __shared__ int sidx[KSEL];
    __shared__ float sval[KSEL];
    const int b = blockIdx.x;
    const int row = rowStart + b;
    const int t = threadIdx.x;
    if (t < KSEL) {
        sidx[t] = idxL[(size_t)b * KSEL + t];
        sval[t] = valL[(size_t)b * KSEL + t];
    }
    __syncthreads();
    float acc0 = bd[t];
    float acc1 = bd[t + 256];
    float acc2 = bd[t + 512];
#pragma unroll 4
    for (int k = 0; k < KSEL; ++k) {
        const float* col = AdnT + (size_t)sidx[k] * DD;
        float v = sval[k];
        acc0 += v * col[t];
        acc1 += v * col[t + 256];
        acc2 += v * col[t + 512];
    }
    out[(size_t)row * DD + t] = acc0;
    out[(size_t)row * DD + t + 256] = acc1;
    out[(size_t)row * DD + t + 512] = acc2;
}

// ---------------------------------------------------------------------------
extern "C" void kernel_launch(void* const* d_in, const int* in_sizes, int n_in,
                              void* d_out, int out_size, void* d_ws, size_t ws_size,
                              hipStream_t stream) {
    const float* x  = (const float*)d_in[0];   // [B, D]
    const float* Ad = (const float*)d_in[1];   // [D, W]
    const float* bd = (const float*)d_in[2];   // [1, D]
    float* out = (float*)d_out;                // [B, D]

    const size_t ADNT_B = (size_t)WW * DD * 4;        // 25,165,824
    const size_t NRM_B  = (size_t)WW * 4;             // 32,768
    const size_t IDX_B  = (size_t)BBATCH * KSEL * 4;  // 1,048,576
    const size_t VAL_B  = IDX_B;
    const size_t G_B    = (size_t)WW * WW * 4;        // 268,435,456 (= 256 MiB)
    const size_t ZROW_B = (size_t)WW * 4;             // 32,768
    const size_t A_MIN  = ADNT_B + NRM_B + IDX_B + VAL_B + G_B + 128 * ZROW_B;

    if (ws_size >= A_MIN) {
        // ---------------- Layout A: everything in ws ----------------
        char* p = (char*)d_ws;
        float* AdnT = (float*)p;  p += ADNT_B;
        float* nrm  = (float*)p;  p += NRM_B;
        int*   idxL = (int*)p;    p += IDX_B;
        float* valL = (float*)p;  p += VAL_B;
        float* G    = (float*)p;  p += G_B;
        float* z    = (float*)p;
        size_t z_avail = ws_size - (ADNT_B + NRM_B + IDX_B + VAL_B + G_B);
        int chunk = (int)((z_avail / ZROW_B) / 128) * 128;
        if (chunk > BBATCH) chunk = BBATCH;

        colnorm_kernel<<<WW / 256, 256, 0, stream>>>(Ad, nrm);
        gram_tn_f64_kernel<<<dim3(WW / 64, WW / 128), 256, 0, stream>>>(Ad, nrm, G);
        mirror_kernel<<<dim3(WW / 64, WW / 64), 256, 0, stream>>>(G);
        for (int r0 = 0; r0 < BBATCH; r0 += chunk) {
            int rows = (BBATCH - r0 < chunk) ? (BBATCH - r0) : chunk;
            z_nn_f64_kernel<<<dim3(WW / 64, rows / 128), 256, 0, stream>>>(
                x + (size_t)r0 * DD, Ad, bd, nrm, z);
            mp_loop_kernel<<<rows, 256, 0, stream>>>(
                z, G, idxL + (size_t)r0 * KSEL, valL + (size_t)r0 * KSEL);
        }
        transpose_scale_kernel<<<dim3(WW / 32, DD / 32), dim3(32, 8), 0, stream>>>(Ad, nrm, AdnT);
        assemble_kernel<<<BBATCH, 256, 0, stream>>>(AdnT, bd, idxL, valL, out, 0);
    } else if (ws_size >= G_B) {
        // ---------------- Layout B: ws = G only; scratch in d_out ----------------
        // d_out carve (25,165,824 B total):
        //   [0 .. 20,971,520)          z chunks (640 rows x 32 KB)
        //   [20,971,520 .. 21,004,288) nrm (32 KB)
        //   [23,068,672 .. 24,117,248) idxL [B,32]
        //   [24,117,248 .. 25,165,824) valL [B,32]
        float* G    = (float*)d_ws;
        char*  ob   = (char*)d_out;
        float* z    = (float*)ob;
        float* nrm  = (float*)(ob + 20971520);
        int*   idxL = (int*)(ob + 23068672);
        float* valL = (float*)(ob + 24117248);
        // after MP loops, G is dead -> reuse ws:
        float* AdnT = (float*)d_ws;
        int*   idx2 = (int*)((char*)d_ws + ADNT_B);
        float* val2 = (float*)((char*)d_ws + ADNT_B + IDX_B);
        const int chunk = 640;   // 5 x 128; last chunk 512 = 4 x 128

        colnorm_kernel<<<WW / 256, 256, 0, stream>>>(Ad, nrm);
        gram_tn_f64_kernel<<<dim3(WW / 64, WW / 128), 256, 0, stream>>>(Ad, nrm, G);
        mirror_kernel<<<dim3(WW / 64, WW / 64), 256, 0, stream>>>(G);
        for (int r0 = 0; r0 < BBATCH; r0 += chunk) {
            int rows = (BBATCH - r0 < chunk) ? (BBATCH - r0) : chunk;
            z_nn_f64_kernel<<<dim3(WW / 64, rows / 128), 256, 0, stream>>>(
                x + (size_t)r0 * DD, Ad, bd, nrm, z);
            mp_loop_kernel<<<rows, 256, 0, stream>>>(
                z, G, idxL + (size_t)r0 * KSEL, valL + (size_t)r0 * KSEL);
        }
        // relocate metadata into ws (G dead), build AdnT in ws, then one
        // hazard-free assemble overwrites d_out.
        {
            int n = BBATCH * KSEL;
            copy_meta_kernel<<<(n + 255) / 256, 256, 0, stream>>>(idxL, valL, idx2, val2, n);
        }
        transpose_scale_kernel<<<dim3(WW / 32, DD / 32), dim3(32, 8), 0, stream>>>(Ad, nrm, AdnT);
        assemble_kernel<<<BBATCH, 256, 0, stream>>>(AdnT, bd, idx2, val2, out, 0);
    }
    // else: ws too small for any fp32-G plan -> leave output zeroed (clean fail)
}

// Round 10
// 5038.782 us; speedup vs baseline: 1.4048x; 1.1160x over previous
//
#include <hip/hip_runtime.h>
#include <cstddef>

// Problem constants (fixed by the reference)
static const int WW = 8192;     // width (atoms)
static const int DD = 768;      // input dim
static const int BBATCH = 8192; // batch
static const int KSEL = 32;     // MP steps

// ---------------------------------------------------------------------------
// column norms of Ad [D, W] -> nrm[W] = max(||Ad[:,w]||, 1e-8), fp64 accumulate
// ---------------------------------------------------------------------------
__global__ __launch_bounds__(256) void colnorm_kernel(const float* __restrict__ Ad,
                                                      float* __restrict__ nrm) {
    int w = blockIdx.x * 256 + threadIdx.x;
    double s = 0.0;
    for (int d = 0; d < DD; ++d) {
        double v = (double)Ad[(size_t)d * WW + w];
        s += v * v;
    }
    nrm[w] = fmaxf((float)sqrt(s), 1e-8f);
}

// ---------------------------------------------------------------------------
// AdnT[w, d] = Ad[d, w] / nrm[w]   (LDS tiled transpose, 32x32)
// ---------------------------------------------------------------------------
__global__ __launch_bounds__(256) void transpose_scale_kernel(const float* __restrict__ Ad,
                                                              const float* __restrict__ nrm,
                                                              float* __restrict__ AdnT) {
    __shared__ float tile[32][33];
    int wb = blockIdx.x * 32;
    int db = blockIdx.y * 32;
    int tx = threadIdx.x;   // 0..31
    int ty = threadIdx.y;   // 0..7
    for (int i = ty; i < 32; i += 8)
        tile[i][tx] = Ad[(size_t)(db + i) * WW + (wb + tx)];
    __syncthreads();
    for (int i = ty; i < 32; i += 8)
        AdnT[(size_t)(wb + i) * DD + (db + tx)] = tile[tx][i] / nrm[wb + i];
}

// ---------------------------------------------------------------------------
// Gram (TN, fp64): G[i,j] = (sum_d Ad[d,i]*Ad[d,j]) / (nrm[i]*nrm[j])
// 128x64 tile, BK=16, 256 threads, 8x4 f64 microtile.
// BOTH operands staged as f64 via lane-contiguous double2 writes (conflict-
// free; each wave writes whole contiguous rows) -> ZERO cvt in inner loop.
// Upper-region blocks only (bx >= 2*by); mirror fills strict-lower tiles.
// Per-element k-order identical to R5/R8/R9 -> bitwise-same G.
// ---------------------------------------------------------------------------
__global__ __launch_bounds__(256) void gram_tn_f64_kernel(const float* __restrict__ Ad,
                                                          const float* __restrict__ nrm,
                                                          float* __restrict__ G) {
    const int bx = blockIdx.x, by = blockIdx.y;
    if (bx < 2 * by) return;   // block entirely strictly-lower -> skip
    __shared__ __align__(16) double As[16 * 130];   // As[k][i], i=0..127
    __shared__ __align__(16) double Bs[16 * 66];    // Bs[k][j], j=0..63
    const int tid = threadIdx.x;
    const int tx = tid & 15;         // 0..15 (col group)
    const int ty = tid >> 4;         // 0..15 (row group)
    const int i0 = by * 128;
    const int j0 = bx * 64;
    // A staging: slot q (0..3): idx = tid+256q -> row idx>>6 (0..15), pos (idx&63)*2
    const int ar0 = tid >> 6;        // 0..3 (wave id)
    const int ap0 = (tid & 63) * 2;  // 0..126
    // B staging: brow 0..7 (+8 second half), bpos lane-contiguous
    const int brow = tid >> 5;       // 0..7
    const int bpos = (tid & 31) * 2; // 0..62

    double acc[8][4];
#pragma unroll
    for (int i = 0; i < 8; ++i)
#pragma unroll
        for (int j = 0; j < 4; ++j) acc[i][j] = 0.0;

    for (int k0 = 0; k0 < DD; k0 += 16) {
        float2 aL[4];
#pragma unroll
        for (int q = 0; q < 4; ++q)
            aL[q] = *(const float2*)&Ad[(size_t)(k0 + 4 * q + ar0) * WW + i0 + ap0];
        float2 bl0 = *(const float2*)&Ad[(size_t)(k0 + brow) * WW + j0 + bpos];
        float2 bl1 = *(const float2*)&Ad[(size_t)(k0 + 8 + brow) * WW + j0 + bpos];
        __syncthreads();   // previous iteration's LDS reads done
#pragma unroll
        for (int q = 0; q < 4; ++q) {
            double2 d; d.x = (double)aL[q].x; d.y = (double)aL[q].y;
            *(double2*)&As[(4 * q + ar0) * 130 + ap0] = d;
        }
        {
            double2 d0; d0.x = (double)bl0.x; d0.y = (double)bl0.y;
            double2 d1; d1.x = (double)bl1.x; d1.y = (double)bl1.y;
            *(double2*)&Bs[brow * 66 + bpos] = d0;
            *(double2*)&Bs[(8 + brow) * 66 + bpos] = d1;
        }
        __syncthreads();

#pragma unroll
        for (int kk = 0; kk < 16; ++kk) {
            const double* arw = &As[kk * 130];
            const double* bb = &Bs[kk * 66];
            double av[8] = {arw[ty * 4 + 0], arw[ty * 4 + 1],
                            arw[ty * 4 + 2], arw[ty * 4 + 3],
                            arw[64 + ty * 4 + 0], arw[64 + ty * 4 + 1],
                            arw[64 + ty * 4 + 2], arw[64 + ty * 4 + 3]};
            double bv[4] = {bb[tx], bb[16 + tx], bb[32 + tx], bb[48 + tx]};
#pragma unroll
            for (int i = 0; i < 8; ++i)
#pragma unroll
                for (int j = 0; j < 4; ++j) acc[i][j] += av[i] * bv[j];
        }
    }

#pragma unroll
    for (int band = 0; band < 2; ++band) {
#pragma unroll
        for (int i = 0; i < 4; ++i) {
            int row = i0 + band * 64 + ty * 4 + i;
            double inv_i = 1.0 / (double)nrm[row];
            int ar = band * 4 + i;
#pragma unroll
            for (int j = 0; j < 4; ++j) {
                int col = j0 + j * 16 + tx;
                G[(size_t)row * WW + col] = (float)(acc[ar][j] * inv_i / (double)nrm[col]);
            }
        }
    }
}

// ---------------------------------------------------------------------------
// mirror: G[j,i] = G[i,j] for strict-upper 64x64 tiles (bitwise-exact copy)
// ---------------------------------------------------------------------------
__global__ __launch_bounds__(256) void mirror_kernel(float* __restrict__ G) {
    const int ti = blockIdx.y;
    const int tj = blockIdx.x;
    if (tj <= ti) return;
    __shared__ float tile[64][65];
    const int t = threadIdx.x;
    const int c4 = (t & 15) * 4;   // 0..60
    const int r  = t >> 4;         // 0..15
#pragma unroll
    for (int rr = r; rr < 64; rr += 16) {
        float4 v = *(const float4*)&G[(size_t)(ti * 64 + rr) * WW + tj * 64 + c4];
        tile[rr][c4 + 0] = v.x;
        tile[rr][c4 + 1] = v.y;
        tile[rr][c4 + 2] = v.z;
        tile[rr][c4 + 3] = v.w;
    }
    __syncthreads();
#pragma unroll
    for (int rr = r; rr < 64; rr += 16) {
        float4 v = make_float4(tile[c4 + 0][rr], tile[c4 + 1][rr],
                               tile[c4 + 2][rr], tile[c4 + 3][rr]);
        *(float4*)&G[(size_t)(tj * 64 + rr) * WW + ti * 64 + c4] = v;
    }
}

// ---------------------------------------------------------------------------
// z (NN, fp64): Z[b,w] = (sum_d (X[b,d]-bd[d]) * Ad[d,w]) / nrm[w]
// 128x64 tile, 8x4 f64 microtile; A (=X-bd) staged transposed As[k][b] as f64
// (scalar b64 writes, <=2-way banks = free), B staged f64 double2-contiguous.
// Zero cvt in the inner loop. Numerics identical to R9 (f32 subtract, exact
// f64 promotion, same FMA order).
// ---------------------------------------------------------------------------
__global__ __launch_bounds__(256) void z_nn_f64_kernel(const float* __restrict__ X,
                                                       const float* __restrict__ Ad,
                                                       const float* __restrict__ bd,
                                                       const float* __restrict__ nrm,
                                                       float* __restrict__ Z) {
    __shared__ __align__(16) double As[16 * 130];   // As[k][b]
    __shared__ __align__(16) double Bs[16 * 66];    // Bs[k][w]
    const int tid = threadIdx.x;
    const int tx = tid & 15;
    const int ty = tid >> 4;
    const int b0 = blockIdx.y * 128;
    const int w0 = blockIdx.x * 64;
    const int r  = tid >> 1;         // 0..127 (A staging batch-row)
    const int k8 = (tid & 1) * 8;    // 0 or 8 (A staging k offset)
    const int brow = tid >> 5;       // 0..7
    const int bpos = (tid & 31) * 2; // 0..62

    double acc[8][4];
#pragma unroll
    for (int i = 0; i < 8; ++i)
#pragma unroll
        for (int j = 0; j < 4; ++j) acc[i][j] = 0.0;

    for (int k0 = 0; k0 < DD; k0 += 16) {
        float4 bias0 = *(const float4*)&bd[k0 + k8];
        float4 bias1 = *(const float4*)&bd[k0 + k8 + 4];
        float4 a0 = *(const float4*)&X[(size_t)(b0 + r) * DD + k0 + k8];
        float4 a1 = *(const float4*)&X[(size_t)(b0 + r) * DD + k0 + k8 + 4];
        a0.x -= bias0.x; a0.y -= bias0.y; a0.z -= bias0.z; a0.w -= bias0.w;
        a1.x -= bias1.x; a1.y -= bias1.y; a1.z -= bias1.z; a1.w -= bias1.w;
        float2 bl0 = *(const float2*)&Ad[(size_t)(k0 + brow) * WW + w0 + bpos];
        float2 bl1 = *(const float2*)&Ad[(size_t)(k0 + 8 + brow) * WW + w0 + bpos];
        __syncthreads();
        As[(k8 + 0) * 130 + r] = (double)a0.x;
        As[(k8 + 1) * 130 + r] = (double)a0.y;
        As[(k8 + 2) * 130 + r] = (double)a0.z;
        As[(k8 + 3) * 130 + r] = (double)a0.w;
        As[(k8 + 4) * 130 + r] = (double)a1.x;
        As[(k8 + 5) * 130 + r] = (double)a1.y;
        As[(k8 + 6) * 130 + r] = (double)a1.z;
        As[(k8 + 7) * 130 + r] = (double)a1.w;
        {
            double2 d0; d0.x = (double)bl0.x; d0.y = (double)bl0.y;
            double2 d1; d1.x = (double)bl1.x; d1.y = (double)bl1.y;
            *(double2*)&Bs[brow * 66 + bpos] = d0;
            *(double2*)&Bs[(8 + brow) * 66 + bpos] = d1;
        }
        __syncthreads();

#pragma unroll
        for (int kk = 0; kk < 16; ++kk) {
            const double* arw = &As[kk * 130];
            const double* bb = &Bs[kk * 66];
            double av[8] = {arw[ty * 4 + 0], arw[ty * 4 + 1],
                            arw[ty * 4 + 2], arw[ty * 4 + 3],
                            arw[64 + ty * 4 + 0], arw[64 + ty * 4 + 1],
                            arw[64 + ty * 4 + 2], arw[64 + ty * 4 + 3]};
            double bv[4] = {bb[tx], bb[16 + tx], bb[32 + tx], bb[48 + tx]};
#pragma unroll
            for (int i = 0; i < 8; ++i)
#pragma unroll
                for (int j = 0; j < 4; ++j) acc[i][j] += av[i] * bv[j];
        }
    }

#pragma unroll
    for (int band = 0; band < 2; ++band) {
#pragma unroll
        for (int i = 0; i < 4; ++i) {
            int row = b0 + band * 64 + ty * 4 + i;
            int ar = band * 4 + i;
#pragma unroll
            for (int j = 0; j < 4; ++j) {
                int col = w0 + j * 16 + tx;
                Z[(size_t)row * WW + col] = (float)(acc[ar][j] / (double)nrm[col]);
            }
        }
    }
}

// ---------------------------------------------------------------------------
// Fused MP loop. One block per batch row; z-row in LDS for all 32 steps.
// Argmax tracking fused into the rank-1 update pass; wave64 shfl butterfly
// reduce + 4-partial LDS resolve -> 2 barriers per step.
// ---------------------------------------------------------------------------
__global__ __launch_bounds__(256) void mp_loop_kernel(const float* __restrict__ z0,
                                                      const float* __restrict__ G,
                                                      int* __restrict__ idxL,
                                                      float* __restrict__ valL) {
    __shared__ __align__(16) float zrow[WW];   // 32 KB
    __shared__ float wv[4];
    __shared__ int   wi[4];
    const int b = blockIdx.x;
    const int t = threadIdx.x;
    float4* zs = (float4*)zrow;

    float best = -1.f;
    int bidx = 0;
    unsigned selmask = 0;   // bit j*4+e: slot (t+256*j) element e is selected

    {
        const float4* zp = (const float4*)(z0 + (size_t)b * WW);
#pragma unroll
        for (int j = 0; j < 8; ++j) {
            int slot = t + 256 * j;
            float4 v = zp[slot];
            zs[slot] = v;
            int w = slot * 4;
            float a0 = fabsf(v.x), a1 = fabsf(v.y), a2 = fabsf(v.z), a3 = fabsf(v.w);
            if (a0 > best) { best = a0; bidx = w; }
            if (a1 > best) { best = a1; bidx = w + 1; }
            if (a2 > best) { best = a2; bidx = w + 2; }
            if (a3 > best) { best = a3; bidx = w + 3; }
        }
    }

    for (int k = 0; k < KSEL; ++k) {
        float v = best;
        int i = bidx;
#pragma unroll
        for (int off = 32; off > 0; off >>= 1) {
            float ov = __shfl_xor(v, off, 64);
            int   oi = __shfl_xor(i, off, 64);
            if (ov > v || (ov == v && oi < i)) { v = ov; i = oi; }
        }
        if ((t & 63) == 0) { wv[t >> 6] = v; wi[t >> 6] = i; }
        __syncthreads();   // A: partials visible; prev phase's zrow writes visible
        float rv = wv[0];
        int   ri = wi[0];
#pragma unroll
        for (int q = 1; q < 4; ++q) {
            float qv = wv[q];
            int   qi = wi[q];
            if (qv > rv || (qv == rv && qi < ri)) { rv = qv; ri = qi; }
        }
        const int idx = ri;
        const float val = zrow[idx];   // pre-update value (LDS broadcast)
        if (t == 0) {
            idxL[(size_t)b * KSEL + k] = idx;
            valL[(size_t)b * KSEL + k] = val;
        }
        if (((idx >> 2) & 255) == t)
            selmask |= 1u << (((idx >> 10) << 2) | (idx & 3));
        if (k == KSEL - 1) break;      // final update is dead work
        __syncthreads();   // B: all threads have read val before zrow changes

        best = -1.f;
        bidx = 0;
        const float4* gr = (const float4*)(G + (size_t)idx * WW);
#pragma unroll
        for (int j = 0; j < 8; ++j) {
            int slot = t + 256 * j;
            float4 g = gr[slot];
            float4 z = zs[slot];
            unsigned m = (selmask >> (j * 4)) & 0xFu;
            float n0 = (m & 1u) ? 0.f : z.x - val * g.x;
            float n1 = (m & 2u) ? 0.f : z.y - val * g.y;
            float n2 = (m & 4u) ? 0.f : z.z - val * g.z;
            float n3 = (m & 8u) ? 0.f : z.w - val * g.w;
            zs[slot] = make_float4(n0, n1, n2, n3);
            int w = slot * 4;
            float a0 = fabsf(n0), a1 = fabsf(n1), a2 = fabsf(n2), a3 = fabsf(n3);
            if (a0 > best) { best = a0; bidx = w; }
            if (a1 > best) { best = a1; bidx = w + 1; }
            if (a2 > best) { best = a2; bidx = w + 2; }
            if (a3 > best) { best = a3; bidx = w + 3; }
        }
    }
}

// ---------------------------------------------------------------------------
// copy idx/val metadata (d_out staging -> ws), element-wise
// ---------------------------------------------------------------------------
__global__ __launch_bounds__(256) void copy_meta_kernel(const int* __restrict__ si,
                                                        const float* __restrict__ sv,
                                                        int* __restrict__ di,
                                                        float* __restrict__ dv,
                                                        int n) {
    int i = blockIdx.x * 256 + threadIdx.x;
    if (i < n) {
        di[i] = si[i];
        dv[i] = sv[i];
    }
}

// ---------------------------------------------------------------------------
// out[row, :] = bd + sum_k val[b,k] * AdnT[idx[b,k], :]
// ---------------------------------------------------------------------------
__global__ __launch_bounds__(256) void assemble_kernel(const float* __restrict__ AdnT,
                                                       const float* __restrict__ bd,
                                                       const int* __restrict__ idxL,
                                                       const float* __restrict__ valL,
                                                       float* __restrict__ out,
                                                       int rowStart) {
    __shared__ int sidx[KSEL];
    __shared__ float sval[KSEL];
    const int b = blockIdx.x;
    const int row = rowStart + b;
    const int t = threadIdx.x;
    if (t < KSEL) {
        sidx[t] = idxL[(size_t)b * KSEL + t];
        sval[t] = valL[(size_t)b * KSEL + t];
    }
    __syncthreads();
    float acc0 = bd[t];
    float acc1 = bd[t + 256];
    float acc2 = bd[t + 512];
#pragma unroll 4
    for (int k = 0; k < KSEL; ++k) {
        const float* col = AdnT + (size_t)sidx[k] * DD;
        float v = sval[k];
        acc0 += v * col[t];
        acc1 += v * col[t + 256];
        acc2 += v * col[t + 512];
    }
    out[(size_t)row * DD + t] = acc0;
    out[(size_t)row * DD + t + 256] = acc1;
    out[(size_t)row * DD + t + 512] = acc2;
}

// ---------------------------------------------------------------------------
extern "C" void kernel_launch(void* const* d_in, const int* in_sizes, int n_in,
                              void* d_out, int out_size, void* d_ws, size_t ws_size,
                              hipStream_t stream) {
    const float* x  = (const float*)d_in[0];   // [B, D]
    const float* Ad = (const float*)d_in[1];   // [D, W]
    const float* bd = (const float*)d_in[2];   // [1, D]
    float* out = (float*)d_out;                // [B, D]

    const size_t ADNT_B = (size_t)WW * DD * 4;        // 25,165,824
    const size_t NRM_B  = (size_t)WW * 4;             // 32,768
    const size_t IDX_B  = (size_t)BBATCH * KSEL * 4;  // 1,048,576
    const size_t VAL_B  = IDX_B;
    const size_t G_B    = (size_t)WW * WW * 4;        // 268,435,456 (= 256 MiB)
    const size_t ZROW_B = (size_t)WW * 4;             // 32,768
    const size_t A_MIN  = ADNT_B + NRM_B + IDX_B + VAL_B + G_B + 128 * ZROW_B;

    if (ws_size >= A_MIN) {
        // ---------------- Layout A: everything in ws ----------------
        char* p = (char*)d_ws;
        float* AdnT = (float*)p;  p += ADNT_B;
        float* nrm  = (float*)p;  p += NRM_B;
        int*   idxL = (int*)p;    p += IDX_B;
        float* valL = (float*)p;  p += VAL_B;
        float* G    = (float*)p;  p += G_B;
        float* z    = (float*)p;
        size_t z_avail = ws_size - (ADNT_B + NRM_B + IDX_B + VAL_B + G_B);
        int chunk = (int)((z_avail / ZROW_B) / 128) * 128;
        if (chunk > BBATCH) chunk = BBATCH;

        colnorm_kernel<<<WW / 256, 256, 0, stream>>>(Ad, nrm);
        gram_tn_f64_kernel<<<dim3(WW / 64, WW / 128), 256, 0, stream>>>(Ad, nrm, G);
        mirror_kernel<<<dim3(WW / 64, WW / 64), 256, 0, stream>>>(G);
        for (int r0 = 0; r0 < BBATCH; r0 += chunk) {
            int rows = (BBATCH - r0 < chunk) ? (BBATCH - r0) : chunk;
            z_nn_f64_kernel<<<dim3(WW / 64, rows / 128), 256, 0, stream>>>(
                x + (size_t)r0 * DD, Ad, bd, nrm, z);
            mp_loop_kernel<<<rows, 256, 0, stream>>>(
                z, G, idxL + (size_t)r0 * KSEL, valL + (size_t)r0 * KSEL);
        }
        transpose_scale_kernel<<<dim3(WW / 32, DD / 32), dim3(32, 8), 0, stream>>>(Ad, nrm, AdnT);
        assemble_kernel<<<BBATCH, 256, 0, stream>>>(AdnT, bd, idxL, valL, out, 0);
    } else if (ws_size >= G_B) {
        // ---------------- Layout B: ws = G only; scratch in d_out ----------------
        // d_out carve (25,165,824 B total):
        //   [0 .. 20,971,520)          z chunks (512 rows x 32 KB used)
        //   [20,971,520 .. 21,004,288) nrm (32 KB)
        //   [23,068,672 .. 24,117,248) idxL [B,32]
        //   [24,117,248 .. 25,165,824) valL [B,32]
        float* G    = (float*)d_ws;
        char*  ob   = (char*)d_out;
        float* z    = (float*)ob;
        float* nrm  = (float*)(ob + 20971520);
        int*   idxL = (int*)(ob + 23068672);
        float* valL = (float*)(ob + 24117248);
        // after MP loops, G is dead -> reuse ws:
        float* AdnT = (float*)d_ws;
        int*   idx2 = (int*)((char*)d_ws + ADNT_B);
        float* val2 = (float*)((char*)d_ws + ADNT_B + IDX_B);
        const int chunk = 512;   // 4 x 128 rows -> 512 blocks = exactly 2/CU

        colnorm_kernel<<<WW / 256, 256, 0, stream>>>(Ad, nrm);
        gram_tn_f64_kernel<<<dim3(WW / 64, WW / 128), 256, 0, stream>>>(Ad, nrm, G);
        mirror_kernel<<<dim3(WW / 64, WW / 64), 256, 0, stream>>>(G);
        for (int r0 = 0; r0 < BBATCH; r0 += chunk) {
            int rows = (BBATCH - r0 < chunk) ? (BBATCH - r0) : chunk;
            z_nn_f64_kernel<<<dim3(WW / 64, rows / 128), 256, 0, stream>>>(
                x + (size_t)r0 * DD, Ad, bd, nrm, z);
            mp_loop_kernel<<<rows, 256, 0, stream>>>(
                z, G, idxL + (size_t)r0 * KSEL, valL + (size_t)r0 * KSEL);
        }
        // relocate metadata into ws (G dead), build AdnT in ws, then one
        // hazard-free assemble overwrites d_out.
        {
            int n = BBATCH * KSEL;
            copy_meta_kernel<<<(n + 255) / 256, 256, 0, stream>>>(idxL, valL, idx2, val2, n);
        }
        transpose_scale_kernel<<<dim3(WW / 32, DD / 32), dim3(32, 8), 0, stream>>>(Ad, nrm, AdnT);
        assemble_kernel<<<BBATCH, 256, 0, stream>>>(AdnT, bd, idx2, val2, out, 0);
    }
    // else: ws too small for any fp32-G plan -> leave output zeroed (clean fail)
}